// Round 1
// baseline (345.232 us; speedup 1.0000x reference)
//
#include <hip/hip_runtime.h>

// Problem constants (fixed by the reference):
//   B=8, HEADS=8, N=3136, D=32, K2=9
constexpr int Bc   = 8;
constexpr int Hh   = 8;
constexpr int Nn   = 3136;
constexpr int Dd   = 32;
constexpr int K2c  = 9;
constexpr int ROWS = Bc * Hh * Nn;          // 200704 flattened (b,h,n) rows
constexpr int ROWS_PER_BLOCK = 8;           // N % 8 == 0 -> h,b uniform per block
constexpr int BLOCK = 256;

__global__ __launch_bounds__(BLOCK, 4)
void swattn_av_kernel(const float* __restrict__ q,          // [B,H,N,D]
                      const float* __restrict__ attn_local, // [B,H,N,K2]
                      const float* __restrict__ v,          // [B,H,N,D,K2]
                      const float* __restrict__ tok,        // [H,D,K2]
                      const float* __restrict__ bias,       // [H,N,K2]
                      float* __restrict__ out) {            // [B,H,N,D]
    __shared__ float T_lds[Dd * K2c];                 // 288 floats, this block's head
    __shared__ float q_lds[ROWS_PER_BLOCK][Dd + 1];   // +1 pad -> conflict-free col reads
    __shared__ float attn_lds[ROWS_PER_BLOCK][K2c];   // 8 x 9 shared attn weights

    const int tid  = threadIdx.x;
    const int base = blockIdx.x * ROWS_PER_BLOCK;     // first global row of this block
    const int h    = (base / Nn) % Hh;                // uniform across the block

    // --- Phase 0: stage learnable_tokens (288) and q rows (8x32), coalesced ---
    T_lds[tid < Dd * K2c ? tid : 0] = tok[h * Dd * K2c + (tid < Dd * K2c ? tid : 0)];
    if (tid < Dd * K2c - BLOCK)  // threads 0..31 load elements 256..287
        T_lds[BLOCK + tid] = tok[h * Dd * K2c + BLOCK + tid];
    {
        const int lrow = tid >> 5, d = tid & 31;
        q_lds[lrow][d] = q[(base + lrow) * Dd + d];
    }
    __syncthreads();

    // --- Phase A: 72 threads compute attn[lrow][k] = q.T_k + bias + local ---
    if (tid < ROWS_PER_BLOCK * K2c) {
        const int lrow = tid / K2c;
        const int k    = tid - lrow * K2c;
        const int gr   = base + lrow;
        float s0 = 0.f, s1 = 0.f, s2 = 0.f, s3 = 0.f;
        #pragma unroll
        for (int d = 0; d < Dd; d += 4) {
            s0 += q_lds[lrow][d + 0] * T_lds[(d + 0) * K2c + k];
            s1 += q_lds[lrow][d + 1] * T_lds[(d + 1) * K2c + k];
            s2 += q_lds[lrow][d + 2] * T_lds[(d + 2) * K2c + k];
            s3 += q_lds[lrow][d + 3] * T_lds[(d + 3) * K2c + k];
        }
        const int bn = gr % (Hh * Nn);                // (h*N + n)
        attn_lds[lrow][k] = ((s0 + s1) + (s2 + s3))
                          + attn_local[gr * K2c + k]
                          + bias[bn * K2c + k];
    }
    __syncthreads();

    // --- Phase B: 256 threads, one output element each: out[gr][d] = attn . v_row ---
    {
        const int lrow = tid >> 5, d = tid & 31;
        const int gr   = base + lrow;
        const float* __restrict__ vr = v + (size_t)gr * (Dd * K2c) + d * K2c;
        float acc = 0.f;
        #pragma unroll
        for (int k = 0; k < K2c; ++k)
            acc += attn_lds[lrow][k] * vr[k];
        out[gr * Dd + d] = acc;
    }
}

extern "C" void kernel_launch(void* const* d_in, const int* in_sizes, int n_in,
                              void* d_out, int out_size, void* d_ws, size_t ws_size,
                              hipStream_t stream) {
    const float* q          = (const float*)d_in[0];   // q_norm          [B,H,N,D]
    const float* attn_local = (const float*)d_in[1];   // attn_local      [B,H,N,K2]
    const float* v          = (const float*)d_in[2];   // v_local         [B,H,N,D,K2]
    const float* tok        = (const float*)d_in[3];   // learnable_tokens[H,D,K2]
    const float* bias       = (const float*)d_in[4];   // learnable_bias  [H,N,K2]
    // d_in[5..7] = window_size, H, W scalars (unused; K2=9 is window^2 baked in)
    float* out = (float*)d_out;

    const int grid = ROWS / ROWS_PER_BLOCK;            // 25088, exact
    swattn_av_kernel<<<grid, BLOCK, 0, stream>>>(q, attn_local, v, tok, bias, out);
}